// Round 12
// baseline (34.758 us; speedup 1.0000x reference)
//
#include <hip/hip_runtime.h>
#include <math.h>

#define T 16
#define A 8
#define H 128
#define E 32
#define G (4*H)   // 512 gate rows per LSTM

typedef _Float16 h2t __attribute__((ext_vector_type(2)));
typedef _Float16 h8t __attribute__((ext_vector_type(8)));

__device__ __forceinline__ float sigmoidf_(float x) {
    return 1.0f / (1.0f + __expf(-x));               // safe at both extremes
}
__device__ __forceinline__ float tanhf_(float x) {
    return 1.0f - 2.0f / (1.0f + __expf(2.0f * x));  // safe at both extremes
}

#if __has_builtin(__builtin_amdgcn_fdot2)
#define DOT2(a, b, c) __builtin_amdgcn_fdot2((a), (b), (c), false)
#else
__device__ __forceinline__ float dot2_fb(h2t a, h2t b, float c) {
    return fmaf((float)a[0], (float)b[0], fmaf((float)a[1], (float)b[1], c));
}
#define DOT2(a, b, c) dot2_fb((a), (b), (c))
#endif

#define RPT16(M) M(0) M(1) M(2) M(3) M(4) M(5) M(6) M(7) \
                 M(8) M(9) M(10) M(11) M(12) M(13) M(14) M(15)
#define RPT8(M)  M(0) M(1) M(2) M(3) M(4) M(5) M(6) M(7)

// Thread k: gate g = k&3 of hidden unit j = k>>2 (weight row r = g*128+j).
// After the dot, unit j's 4 gates are in adjacent lanes -> 3 shfl_xor exchange,
// activation computed redundantly by all 4 lanes, ONE barrier per step.
__global__ __attribute__((amdgpu_flat_work_group_size(512, 512),
                          amdgpu_waves_per_eu(2, 2)))
void ppo_ctrl_kernel(const int* __restrict__ old_actions,
                     const float* __restrict__ init_input,
                     const float* __restrict__ W_ih_a, const float* __restrict__ W_hh_a,
                     const float* __restrict__ b_ih_a, const float* __restrict__ b_hh_a,
                     const float* __restrict__ heads_W, const float* __restrict__ heads_b,
                     const float* __restrict__ W_ih_c, const float* __restrict__ W_hh_c,
                     const float* __restrict__ b_ih_c, const float* __restrict__ b_hh_c,
                     const float* __restrict__ critic_W, const float* __restrict__ critic_b,
                     const float* __restrict__ embed,
                     float* __restrict__ out)
{
    const int tid  = threadIdx.x;
    const int lane = tid & 63;
    const int wv   = tid >> 6;          // 8 waves
    const bool actor = (blockIdx.x == 0);

    const int j = tid >> 2;             // hidden unit 0..127
    const int g = tid & 3;              // gate 0..3 (i,f,g,o)
    const int r = (g << 7) | j;         // weight row

    const float* W_ih = actor ? W_ih_a : W_ih_c;
    const float* W_hh = actor ? W_hh_a : W_hh_c;
    const float* b_ih = actor ? b_ih_a : b_ih_c;
    const float* b_hh = actor ? b_hh_a : b_hh_c;

    __shared__ __align__(16) float accx_s[T * 512];    // 32 KB, same-thread r/w
    __shared__ __align__(16) float x_s[T][E];          // 2 KB
    __shared__ __align__(16) _Float16 h16[H];          // 256 B
    __shared__ __align__(16) _Float16 hhist[T][H];     // 4 KB

    // ---- build x sequence (T*E == 512 == blockDim) ----
    {
        int t0 = tid >> 5, e0 = tid & 31;
        float v = (t0 == 0) ? init_input[e0]
                            : embed[((t0 - 1) * A + old_actions[t0 - 1]) * E + e0];
        x_s[t0][e0] = v;
    }
    if (tid < 64) ((unsigned*)h16)[tid] = 0u;   // zero 256 B

    // ---- W_hh row r -> 16 pinned h8t regs (f32 load, cvt f16) ----
    const float* rowp = W_hh + r * H;
#define LOADW(i) h8t w##i; {                                              \
        float4 fa = *(const float4*)(rowp + 8*(i));                       \
        float4 fb = *(const float4*)(rowp + 8*(i) + 4);                   \
        w##i = (h8t){ (_Float16)fa.x, (_Float16)fa.y,                     \
                      (_Float16)fa.z, (_Float16)fa.w,                     \
                      (_Float16)fb.x, (_Float16)fb.y,                     \
                      (_Float16)fb.z, (_Float16)fb.w };                   \
        asm volatile("" : "+v"(w##i)); }
    RPT16(LOADW)
#undef LOADW

    // ---- W_ih row (transient) + bias ----
    const float* wir = W_ih + r * E;
    float4 wi0 = *(const float4*)(wir +  0), wi1 = *(const float4*)(wir +  4),
           wi2 = *(const float4*)(wir +  8), wi3 = *(const float4*)(wir + 12),
           wi4 = *(const float4*)(wir + 16), wi5 = *(const float4*)(wir + 20),
           wi6 = *(const float4*)(wir + 24), wi7 = *(const float4*)(wir + 28);
    const float bias = b_ih[r] + b_hh[r];

    __syncthreads();   // x_s, h16 ready

    // ---- accx_s[t*512+tid] = bias + W_ih[r]@x(t) (same-thread r/w) ----
    #pragma unroll 2
    for (int t = 0; t < T; ++t) {
        float s0 = 0.f, s1 = 0.f, s2 = 0.f, s3 = 0.f;
#define MACI(i) { float4 xv = *(const float4*)(&x_s[t][4*(i)]);           \
        s0 = fmaf(wi##i.x, xv.x, s0); s1 = fmaf(wi##i.y, xv.y, s1);       \
        s2 = fmaf(wi##i.z, xv.z, s2); s3 = fmaf(wi##i.w, xv.w, s3); }
        MACI(0) MACI(1) MACI(2) MACI(3) MACI(4) MACI(5) MACI(6) MACI(7)
#undef MACI
        accx_s[t * 512 + tid] = bias + ((s0 + s1) + (s2 + s3));
    }

    // ---- heads prefetch (pinned; consumed after the loop) ----
    const int tt0 = wv, tt1 = wv + 8;
#define HWLOAD(a) \
    float hl0##a = heads_W[(tt0 * A + (a)) * H + lane]; \
    float hh0##a = heads_W[(tt0 * A + (a)) * H + 64 + lane]; \
    float hl1##a = heads_W[(tt1 * A + (a)) * H + lane]; \
    float hh1##a = heads_W[(tt1 * A + (a)) * H + 64 + lane]; \
    asm volatile("" : "+v"(hl0##a), "+v"(hh0##a), "+v"(hl1##a), "+v"(hh1##a));
    RPT8(HWLOAD)
#undef HWLOAD
    float hbv0 = heads_b[tt0 * A + (lane & 7)];
    float hbv1 = heads_b[tt1 * A + (lane & 7)];
    float cw0 = critic_W[lane], cw1 = critic_W[64 + lane], cb = critic_b[0];
    int act0 = old_actions[tt0], act1 = old_actions[tt1];
    asm volatile("" : "+v"(hbv0), "+v"(hbv1), "+v"(cw0), "+v"(cw1), "+v"(cb));

    float c_reg = 0.0f;                      // cell state, replicated per 4-lane group
    const h8t* hv = (const h8t*)h16;         // broadcast reads: conflict-free
    const bool b0 = (g & 1) != 0, b1 = (g & 2) != 0;

    // ---- 16 sequential steps; ONE barrier per step, no idle waves ----
    #pragma unroll 1
    for (int t = 0; t < T; ++t) {
        float p = accx_s[t * 512 + tid];
        if (t != 0) {                        // t==0: h==0 -> dot is zero
            float a0 = 0.f, a1 = 0.f, a2 = 0.f, a3 = 0.f;
#define MACC(i) { h8t hq = hv[i];                                          \
            a0 = DOT2(__builtin_shufflevector(w##i, w##i, 0, 1),           \
                      __builtin_shufflevector(hq,  hq,  0, 1), a0);        \
            a1 = DOT2(__builtin_shufflevector(w##i, w##i, 2, 3),           \
                      __builtin_shufflevector(hq,  hq,  2, 3), a1);        \
            a2 = DOT2(__builtin_shufflevector(w##i, w##i, 4, 5),           \
                      __builtin_shufflevector(hq,  hq,  4, 5), a2);        \
            a3 = DOT2(__builtin_shufflevector(w##i, w##i, 6, 7),           \
                      __builtin_shufflevector(hq,  hq,  6, 7), a3); }
            RPT16(MACC)
#undef MACC
            p += ((a0 + a1) + (a2 + a3));
        }

        // exchange the 4 gates within the 4-lane group (no LDS, no extra barrier)
        float q1 = __shfl_xor(p, 1);
        float q2 = __shfl_xor(p, 2);
        float q3 = __shfl_xor(q1, 2);
        // lane g holds: p=gate g, q1=gate g^1, q2=gate g^2, q3=gate g^3
        float gi = b1 ? (b0 ? q3 : q2) : (b0 ? q1 : p);
        float gf = b1 ? (b0 ? q2 : q3) : (b0 ? p  : q1);
        float gg = b1 ? (b0 ? q1 : p ) : (b0 ? q3 : q2);
        float go = b1 ? (b0 ? p  : q1) : (b0 ? q2 : q3);

        float cn = sigmoidf_(gf) * c_reg + sigmoidf_(gi) * tanhf_(gg);
        c_reg = cn;
        float hvv = sigmoidf_(go) * tanhf_(cn);
        _Float16 hf = (_Float16)hvv;
        if (g == 0) {                        // one writer per unit
            h16[j] = hf;
            hhist[t][j] = hf;
        }
        __syncthreads();
    }

    // ---- heads epilogue: zero global loads ----
    if (actor) {
#define LOGIT(rep,a,dst) {                                                \
        float pp = fmaf(hl##rep##a, hA, hh##rep##a * hB);                 \
        pp += __shfl_xor(pp, 1);  pp += __shfl_xor(pp, 2);                \
        pp += __shfl_xor(pp, 4);  pp += __shfl_xor(pp, 8);                \
        pp += __shfl_xor(pp, 16); pp += __shfl_xor(pp, 32);               \
        dst = pp + __shfl(hbv##rep, (a)); }
#define HEADS(rep) {                                                      \
        const int tt = tt##rep;                                           \
        float hA = (float)hhist[tt][lane];                                \
        float hB = (float)hhist[tt][64 + lane];                           \
        float l0,l1,l2,l3,l4,l5,l6,l7;                                    \
        LOGIT(rep,0,l0) LOGIT(rep,1,l1) LOGIT(rep,2,l2) LOGIT(rep,3,l3)   \
        LOGIT(rep,4,l4) LOGIT(rep,5,l5) LOGIT(rep,6,l6) LOGIT(rep,7,l7)   \
        if (lane == 0) {                                                  \
            float m = fmaxf(fmaxf(fmaxf(l0, l1), fmaxf(l2, l3)),          \
                            fmaxf(fmaxf(l4, l5), fmaxf(l6, l7)));         \
            float e0 = __expf(l0 - m), e1 = __expf(l1 - m),               \
                  e2 = __expf(l2 - m), e3 = __expf(l3 - m),               \
                  e4 = __expf(l4 - m), e5 = __expf(l5 - m),               \
                  e6 = __expf(l6 - m), e7 = __expf(l7 - m);               \
            float s = ((e0 + e1) + (e2 + e3)) + ((e4 + e5) + (e6 + e7));  \
            float logZ = m + __logf(s);                                   \
            int act = act##rep;                                           \
            float la = (act == 0) ? l0 : (act == 1) ? l1 : (act == 2) ? l2 : \
                       (act == 3) ? l3 : (act == 4) ? l4 : (act == 5) ? l5 : \
                       (act == 6) ? l6 : l7;                              \
            out[tt] = la - logZ;                                          \
            float w_ = e0*(l0-logZ) + e1*(l1-logZ) + e2*(l2-logZ) + e3*(l3-logZ) \
                     + e4*(l4-logZ) + e5*(l5-logZ) + e6*(l6-logZ) + e7*(l7-logZ); \
            out[T + tt] = -w_ / s;                                        \
        } }
        HEADS(0)
        HEADS(1)
#undef HEADS
#undef LOGIT
    } else {
        #pragma unroll
        for (int rep = 0; rep < 2; ++rep) {
            const int tt = (rep == 0) ? tt0 : tt1;
            float hA = (float)hhist[tt][lane];
            float hB = (float)hhist[tt][64 + lane];
            float p = fmaf(cw0, hA, cw1 * hB);
            p += __shfl_xor(p, 1);  p += __shfl_xor(p, 2);
            p += __shfl_xor(p, 4);  p += __shfl_xor(p, 8);
            p += __shfl_xor(p, 16); p += __shfl_xor(p, 32);
            if (lane == 0) out[2 * T + tt] = p + cb;   // values
        }
    }
}

extern "C" void kernel_launch(void* const* d_in, const int* in_sizes, int n_in,
                              void* d_out, int out_size, void* d_ws, size_t ws_size,
                              hipStream_t stream) {
    const int*   old_actions = (const int*)  d_in[0];
    const float* init_input  = (const float*)d_in[1];
    const float* W_ih_a      = (const float*)d_in[2];
    const float* W_hh_a      = (const float*)d_in[3];
    const float* b_ih_a      = (const float*)d_in[4];
    const float* b_hh_a      = (const float*)d_in[5];
    const float* heads_W     = (const float*)d_in[6];
    const float* heads_b     = (const float*)d_in[7];
    const float* W_ih_c      = (const float*)d_in[8];
    const float* W_hh_c      = (const float*)d_in[9];
    const float* b_ih_c      = (const float*)d_in[10];
    const float* b_hh_c      = (const float*)d_in[11];
    const float* critic_W    = (const float*)d_in[12];
    const float* critic_b    = (const float*)d_in[13];
    const float* embed       = (const float*)d_in[14];
    float* out = (float*)d_out;

    ppo_ctrl_kernel<<<dim3(2), dim3(512), 0, stream>>>(
        old_actions, init_input,
        W_ih_a, W_hh_a, b_ih_a, b_hh_a,
        heads_W, heads_b,
        W_ih_c, W_hh_c, b_ih_c, b_hh_c,
        critic_W, critic_b, embed, out);
}